// Round 6
// baseline (171.637 us; speedup 1.0000x reference)
//
#include <hip/hip_runtime.h>
#include <math.h>

#define L_ 2
#define BAT_ 32
#define A_ 64
#define B_ 1024
#define D_ 128
#define NBITS_ 1024
#define NW 32                 // u32 words per code (1024 bits)
#define NQROWS (L_*BAT_*A_)   // 4096
#define NDROWS (L_*BAT_*B_)   // 65536
#define NROWS (NQROWS + NDROWS) // 69632
#define NAGRP (NROWS / 16)    // 4352 A-row groups of 16
#define NBGRP (NBITS_ / 16)   // 64 bit groups of 16

#define TM 64                 // rows per tile (R6: 256-thread blocks)
#define TN 128                // bits per tile
#define NXB (NROWS / TM)      // 1088 x-tiles
#define NYB (NBITS_ / TN)     // 8 y-tiles
#define XPX (NXB / 8)         // 136 x-tiles per XCD
#define NTPB 4                // x-tiles per block (136 % 4 == 0)

typedef __bf16 bf16x8 __attribute__((ext_vector_type(8)));
typedef float  f32x4  __attribute__((ext_vector_type(4)));

// ---- Stage 0: split fp32 -> bf16 hi/lo AND swizzle into MFMA fragment order.
// Per 16-row group: layout [cbi:8][quad:4][col:16][8 bf16] = 4096 bf16 (8 KB).
// Chunk index c = ks*16 + hl*8 + kk*4 + quad maps to source fp32
// k-offset ks*64 + kk*32 + quad*8 (hi if hl=0, lo if hl=1); cbi = c>>2.
__global__ __launch_bounds__(256) void preswz_kernel(
    const float* __restrict__ qe, const float* __restrict__ de,
    const float* __restrict__ r, __bf16* __restrict__ asw,
    __bf16* __restrict__ rsw)
{
    const int g = blockIdx.x;       // 0..4415: A groups then r groups
    const int t = threadIdx.x;
    const int ks = t >> 7, kk = (t >> 6) & 1, quad = (t >> 4) & 3, col = t & 15;

    const float* src;
    __bf16* dst;
    if (g < NAGRP) {
        int row = g * 16 + col;
        src = (row < NQROWS) ? (qe + (size_t)row * D_)
                             : (de + (size_t)(row - NQROWS) * D_);
        dst = asw + (size_t)g * 4096;
    } else {
        int bit = (g - NAGRP) * 16 + col;
        src = r + (size_t)bit * D_;
        dst = rsw + (size_t)(g - NAGRP) * 4096;
    }

    const int ko = ks * 64 + kk * 32 + quad * 8;
    float4 v0 = *(const float4*)(src + ko);
    float4 v1 = *(const float4*)(src + ko + 4);
    bf16x8 hi, lo;
    hi[0] = (__bf16)v0.x; hi[1] = (__bf16)v0.y;
    hi[2] = (__bf16)v0.z; hi[3] = (__bf16)v0.w;
    hi[4] = (__bf16)v1.x; hi[5] = (__bf16)v1.y;
    hi[6] = (__bf16)v1.z; hi[7] = (__bf16)v1.w;
    lo[0] = (__bf16)(v0.x - (float)hi[0]);
    lo[1] = (__bf16)(v0.y - (float)hi[1]);
    lo[2] = (__bf16)(v0.z - (float)hi[2]);
    lo[3] = (__bf16)(v0.w - (float)hi[3]);
    lo[4] = (__bf16)(v1.x - (float)hi[4]);
    lo[5] = (__bf16)(v1.y - (float)hi[5]);
    lo[6] = (__bf16)(v1.z - (float)hi[6]);
    lo[7] = (__bf16)(v1.w - (float)hi[7]);

    const int c_hi = ks * 16 + kk * 4 + quad;   // hl=0
    const int c_lo = c_hi + 8;                  // hl=1
    *(bf16x8*)(dst + (size_t)(c_hi * 16 + col) * 8) = hi;
    *(bf16x8*)(dst + (size_t)(c_lo * 16 + col) * 8) = lo;
}

// ---- Stage 1: LSH sign-hash — B-hi in registers, B-lo in LDS --------------
// R15: R5's proven ITER/BATCH/prefetch/epilogue structure, with the measured
// limiter (fragment traffic: 8 ds_read + 4 glb per 24 MFMA, LDS pipe ~83% as
// loaded as the MFMA pipe) attacked directly:
//  * B-hi (16 frags/wave, 64 VGPR) loaded from L2-resident rsw ONCE into
//    registers and reused across all 4 tiles -> per-ITER ds_reads 8 -> 4.
//  * Only B-lo staged to LDS (32 KB, compacted: group*4096 + c*1024).
//  * 256-thread blocks (TM=64): at ~125 VGPR + 32 AGPR ~= 157 regs this
//    allows 3 blocks/CU (96 KB LDS, 12 waves) vs R5's measured 9.3 waves;
//    finer granularity also cuts wave-skew/tail losses.
//  * XCD mapping & 8-by L2 sharing unchanged (FETCH 19.5MB proven).
__global__ __launch_bounds__(256, 2) void hash_kernel(
    const __bf16* __restrict__ asw, const __bf16* __restrict__ rsw,
    unsigned int* __restrict__ codes_t)
{
    __shared__ __align__(16) unsigned char bsh[32768];   // B-lo only

    const int t = threadIdx.x;
    const int lane = t & 63;
    const int quad = lane >> 4;       // 0..3
    const int col  = lane & 15;       // 0..15
    const int wv   = __builtin_amdgcn_readfirstlane(t >> 6);  // wave 0..3

    const int bid = blockIdx.x;       // 0..2175
    const int xcd = bid & 7;
    const int s   = bid >> 3;         // 0..271
    const int by  = s & 7;
    const int xq  = s >> 3;           // 0..33
    const int bx0 = xcd * XPX + xq * NTPB;

    const int wrow = (wv >> 1) * 32;  // 2 wave-rows of 32
    const int half = wv & 1;          // 2 wave-cols of 64 bits

    // A frag (ti, cbi) at pointer P: P + (ti*8 + cbi)*512 elems
    const __bf16* abase = asw + ((size_t)(bx0 * 4 + (wv >> 1) * 2)) * 4096
                              + (size_t)lane * 8;
#define ALOAD(P, ti, cbi) (*(const bf16x8*)((P) + ((ti) * 8 + (cbi)) * 512))
#define TILE_STRIDE 16384   /* 4 groups * 4096 elems */

    // ---- B-hi: 16 fragments (tj 0..3 x cbi {0,1,4,5}) into registers ----
    const __bf16* bhbase = rsw + ((size_t)(by * 8 + half * 4) * 8) * 512
                               + (size_t)lane * 8;
#define BHLOAD(tj, cbi) (*(const bf16x8*)(bhbase + ((tj) * 8 + (cbi)) * 512))
    bf16x8 bh00 = BHLOAD(0, 0), bh01 = BHLOAD(0, 1),
           bh02 = BHLOAD(0, 4), bh03 = BHLOAD(0, 5);
    bf16x8 bh10 = BHLOAD(1, 0), bh11 = BHLOAD(1, 1),
           bh12 = BHLOAD(1, 4), bh13 = BHLOAD(1, 5);
    bf16x8 bh20 = BHLOAD(2, 0), bh21 = BHLOAD(2, 1),
           bh22 = BHLOAD(2, 4), bh23 = BHLOAD(2, 5);
    bf16x8 bh30 = BHLOAD(3, 0), bh31 = BHLOAD(3, 1),
           bh32 = BHLOAD(3, 4), bh33 = BHLOAD(3, 5);
#undef BHLOAD

    // Prefetch tile-0 iter-0 A frags; they complete by the staging barrier.
    bf16x8 xh0 = ALOAD(abase, 0, 0), xh1 = ALOAD(abase, 1, 0);
    bf16x8 xl0 = ALOAD(abase, 0, 2), xl1 = ALOAD(abase, 1, 2);
    bf16x8 yh0, yh1, yl0, yl1;

    // ---- Stage B-lo (cbi {2,3,6,7} of each group) compacted into LDS ----
    // LDS layout: [group 0..7][c 0..3][64 lanes x 16B]; c maps cbi 2,3,6,7.
    // Per pass p (=group): dest = p*4096 + (t>>6)*1024 + (t&63)*16 = p*4096+t*16
    // (wave-uniform base + lane*16 as required by global_load_lds).
    {
        const int lsub = t >> 6;                   // == wv, wave-uniform
        const int cbi  = lsub < 2 ? lsub + 2 : lsub + 4;
        const char* bsrc = (const char*)rsw + (size_t)by * 65536
                         + (size_t)cbi * 1024 + (size_t)(t & 63) * 16;
        #pragma unroll
        for (int p = 0; p < 8; ++p)
            __builtin_amdgcn_global_load_lds(
                (const __attribute__((address_space(1))) unsigned int*)(bsrc + p * 8192),
                (__attribute__((address_space(3))) unsigned int*)(bsh + p * 4096 + t * 16),
                16, 0, 0);
    }
    __syncthreads();

    // B-lo frag (tj, c): group = half*4 + tj
    const unsigned char* blbase = bsh + half * 16384 + lane * 16;
#define BLLOAD(tj, c) (*(const bf16x8*)(blbase + (tj) * 4096 + (c) * 1024))

#define MFMA __builtin_amdgcn_mfma_f32_16x16x32_bf16
#define BATCH(A0, A1, B0, B1, B2, B3)                       \
    acc[0][0] = MFMA(A0, B0, acc[0][0], 0, 0, 0);           \
    acc[0][1] = MFMA(A0, B1, acc[0][1], 0, 0, 0);           \
    acc[0][2] = MFMA(A0, B2, acc[0][2], 0, 0, 0);           \
    acc[0][3] = MFMA(A0, B3, acc[0][3], 0, 0, 0);           \
    acc[1][0] = MFMA(A1, B0, acc[1][0], 0, 0, 0);           \
    acc[1][1] = MFMA(A1, B1, acc[1][1], 0, 0, 0);           \
    acc[1][2] = MFMA(A1, B2, acc[1][2], 0, 0, 0);           \
    acc[1][3] = MFMA(A1, B3, acc[1][3], 0, 0, 0);

// One (ks,kk) step, c-index C (cbi_h = {0,1,4,5}[C]): prefetch next A frag
// group, read the 4 B-lo frags, then hh/lh on register B-hi, hl on B-lo.
#define ITER(C, BH0, BH1, BH2, BH3, cH0, cH1, cL0, cL1, PBASE, NH, nH0, nH1, nL0, nL1) \
    {                                                                    \
        nH0 = ALOAD(PBASE, 0, NH);       nH1 = ALOAD(PBASE, 1, NH);      \
        nL0 = ALOAD(PBASE, 0, (NH) + 2); nL1 = ALOAD(PBASE, 1, (NH) + 2);\
        bf16x8 c0 = BLLOAD(0, C), c1 = BLLOAD(1, C),                     \
               c2 = BLLOAD(2, C), c3 = BLLOAD(3, C);                     \
        BATCH(cH0, cH1, BH0, BH1, BH2, BH3)   /* hi*hi */                \
        BATCH(cL0, cL1, BH0, BH1, BH2, BH3)   /* lo*hi */                \
        BATCH(cH0, cH1, c0, c1, c2, c3)       /* hi*lo */                \
    }

    #pragma unroll
    for (int i = 0; i < NTPB; ++i) {
        const __bf16* ab = abase + (size_t)i * TILE_STRIDE;
        const __bf16* an = (i + 1 < NTPB) ? (ab + TILE_STRIDE) : ab;

        f32x4 acc[2][4];
        #pragma unroll
        for (int ti = 0; ti < 2; ++ti)
            #pragma unroll
            for (int tj = 0; tj < 4; ++tj)
                acc[ti][tj] = (f32x4){0.f, 0.f, 0.f, 0.f};

        // A-hi cbi sequence over (ks,kk): {0,1,4,5}; B-hi regs paired by C.
        ITER(0, bh00, bh10, bh20, bh30, xh0, xh1, xl0, xl1, ab, 1, yh0, yh1, yl0, yl1)
        ITER(1, bh01, bh11, bh21, bh31, yh0, yh1, yl0, yl1, ab, 4, xh0, xh1, xl0, xl1)
        ITER(2, bh02, bh12, bh22, bh32, xh0, xh1, xl0, xl1, ab, 5, yh0, yh1, yl0, yl1)
        ITER(3, bh03, bh13, bh23, bh33, yh0, yh1, yl0, yl1, an, 0, xh0, xh1, xl0, xl1)

        // Sign-pack via ballot; C/D layout (m89): col=lane&15, row=quad*4+reg.
        // TRANSPOSED store: codes_t[word][row]. No barrier -> epilogue
        // overlaps the next tile's prefetched A loads.
        const int row0 = (bx0 + i) * TM;
        #pragma unroll
        for (int ti = 0; ti < 2; ++ti) {
            #pragma unroll
            for (int rg = 0; rg < 4; ++rg) {
                unsigned long long b[4];
                #pragma unroll
                for (int tj = 0; tj < 4; ++tj)
                    b[tj] = __ballot(acc[ti][tj][rg] > 0.f);
                if (col < 2) {
                    const int w = col;
                    unsigned int lo16 = (unsigned int)(b[2 * w]     >> (16 * quad)) & 0xFFFFu;
                    unsigned int hi16 = (unsigned int)(b[2 * w + 1] >> (16 * quad)) & 0xFFFFu;
                    const int row = row0 + wrow + ti * 16 + quad * 4 + rg;
                    const int wg  = by * 4 + half * 2 + w;
                    codes_t[(size_t)wg * NROWS + row] = lo16 | (hi16 << 16);
                }
            }
        }
    }

#undef ITER
#undef BATCH
#undef MFMA
#undef BLLOAD
#undef ALOAD
}

// ---- Stage 2: Hamming -> cos (HW v_cos) -> mask -> out ---------------------
// UNCHANGED. grid: 2048 blocks, 8 blocks/CU.
__global__ __launch_bounds__(256) void simmat_kernel(
    const unsigned int* __restrict__ codes_t,
    const int* __restrict__ qtok, const int* __restrict__ dtok,
    float* __restrict__ out)
{
    __shared__ unsigned int qc[8 * 36];

    const int blk  = blockIdx.x;
    const int ct   = blk & 3;
    const int asub = (blk >> 2) & 7;
    const int b    = (blk >> 5) & 31;
    const int l    = blk >> 10;
    const int t    = threadIdx.x;

    const int a0 = asub * 8;
    const int qrow0 = (l * BAT_ + b) * A_ + a0;
    if (t < 256) {
        int w = t >> 3, a = t & 7;
        qc[a * 36 + w] = codes_t[(size_t)w * NROWS + qrow0 + a];
    }
    __syncthreads();

    const int c = ct * 256 + t;
    const size_t drow = (size_t)NQROWS + (size_t)(l * BAT_ + b) * B_ + c;
    unsigned int dc[NW];
    #pragma unroll
    for (int w = 0; w < NW; ++w) dc[w] = codes_t[(size_t)w * NROWS + drow];
    const float dm = (dtok[b * B_ + c] != 0) ? 1.f : 0.f;

    float* obase = out + ((size_t)((b * L_ + l) * A_ + a0)) * B_ + c;
    #pragma unroll
    for (int ai = 0; ai < 8; ++ai) {
        int ham = 0;
        #pragma unroll
        for (int m = 0; m < 8; ++m) {
            uint4 qv = *(const uint4*)(&qc[ai * 36 + m * 4]);
            ham += __popc(qv.x ^ dc[4 * m])     + __popc(qv.y ^ dc[4 * m + 1])
                 + __popc(qv.z ^ dc[4 * m + 2]) + __popc(qv.w ^ dc[4 * m + 3]);
        }
        const float qmv = (qtok[b * A_ + a0 + ai] != 0) ? 1.f : 0.f;
        float sim = __cosf((float)M_PI / (float)NBITS_ * (float)ham);
        obase[(size_t)ai * B_] = sim * (qmv * dm);
    }
}

extern "C" void kernel_launch(void* const* d_in, const int* in_sizes, int n_in,
                              void* d_out, int out_size, void* d_ws, size_t ws_size,
                              hipStream_t stream) {
    const float* qe  = (const float*)d_in[0];  // [L,BAT,A,D]
    const float* de  = (const float*)d_in[1];  // [L,BAT,B,D]
    const int* qtok  = (const int*)d_in[2];    // [BAT,A]
    const int* dtok  = (const int*)d_in[3];    // [BAT,B]
    const float* r   = (const float*)d_in[4];  // [NBITS,D]
    float* out = (float*)d_out;                // [BAT,L,A,B] fp32

    // ws: [0, 8.5MB) codes_t | [8.5, 9.0MB) rsw | [9.0MB, +34MB) asw
    unsigned int* codes_t = (unsigned int*)d_ws;                    // 8912896 B
    __bf16* rsw = (__bf16*)((char*)d_ws + 8912896);                 // 524288 B
    __bf16* asw = (__bf16*)((char*)d_ws + 8912896 + 524288);        // 35651584 B

    preswz_kernel<<<NAGRP + NBGRP, 256, 0, stream>>>(qe, de, r, asw, rsw);
    hash_kernel<<<(NXB / NTPB) * NYB, 256, 0, stream>>>(asw, rsw, codes_t);
    simmat_kernel<<<L_ * BAT_ * 8 * 4, 256, 0, stream>>>(codes_t, qtok, dtok, out);
}

// Round 8
// 164.084 us; speedup vs baseline: 1.0460x; 1.0460x over previous
//
#include <hip/hip_runtime.h>
#include <math.h>

#define L_ 2
#define BAT_ 32
#define A_ 64
#define B_ 1024
#define D_ 128
#define NBITS_ 1024
#define NW 32                 // u32 words per code (1024 bits)
#define NQROWS (L_*BAT_*A_)   // 4096
#define NDROWS (L_*BAT_*B_)   // 65536
#define NROWS (NQROWS + NDROWS) // 69632
#define NAGRP (NROWS / 16)    // 4352 A-row groups of 16
#define NBGRP (NBITS_ / 16)   // 64 bit groups of 16

#define TM 128                // rows per tile
#define TN 128                // bits per tile
#define NXB (NROWS / TM)      // 544 x-tiles
#define NYB (NBITS_ / TN)     // 8 y-tiles
#define XPX (NXB / 8)         // 68 x-tiles per XCD
#define NTPB 4                // x-tiles per block (68 % 4 == 0)

typedef __bf16 bf16x8 __attribute__((ext_vector_type(8)));
typedef float  f32x4  __attribute__((ext_vector_type(4)));
typedef int    i32x4  __attribute__((ext_vector_type(4)));

// ---- Stage 0: split fp32 -> bf16 hi/lo AND swizzle into MFMA fragment order.
// UNCHANGED from R5 (verified).
__global__ __launch_bounds__(256) void preswz_kernel(
    const float* __restrict__ qe, const float* __restrict__ de,
    const float* __restrict__ r, __bf16* __restrict__ asw,
    __bf16* __restrict__ rsw)
{
    const int g = blockIdx.x;       // 0..4415: A groups then r groups
    const int t = threadIdx.x;
    const int ks = t >> 7, kk = (t >> 6) & 1, quad = (t >> 4) & 3, col = t & 15;

    const float* src;
    __bf16* dst;
    if (g < NAGRP) {
        int row = g * 16 + col;
        src = (row < NQROWS) ? (qe + (size_t)row * D_)
                             : (de + (size_t)(row - NQROWS) * D_);
        dst = asw + (size_t)g * 4096;
    } else {
        int bit = (g - NAGRP) * 16 + col;
        src = r + (size_t)bit * D_;
        dst = rsw + (size_t)(g - NAGRP) * 4096;
    }

    const int ko = ks * 64 + kk * 32 + quad * 8;
    float4 v0 = *(const float4*)(src + ko);
    float4 v1 = *(const float4*)(src + ko + 4);
    bf16x8 hi, lo;
    hi[0] = (__bf16)v0.x; hi[1] = (__bf16)v0.y;
    hi[2] = (__bf16)v0.z; hi[3] = (__bf16)v0.w;
    hi[4] = (__bf16)v1.x; hi[5] = (__bf16)v1.y;
    hi[6] = (__bf16)v1.z; hi[7] = (__bf16)v1.w;
    lo[0] = (__bf16)(v0.x - (float)hi[0]);
    lo[1] = (__bf16)(v0.y - (float)hi[1]);
    lo[2] = (__bf16)(v0.z - (float)hi[2]);
    lo[3] = (__bf16)(v0.w - (float)hi[3]);
    lo[4] = (__bf16)(v1.x - (float)hi[4]);
    lo[5] = (__bf16)(v1.y - (float)hi[5]);
    lo[6] = (__bf16)(v1.z - (float)hi[6]);
    lo[7] = (__bf16)(v1.w - (float)hi[7]);

    const int c_hi = ks * 16 + kk * 4 + quad;   // hl=0
    const int c_lo = c_hi + 8;                  // hl=1
    *(bf16x8*)(dst + (size_t)(c_hi * 16 + col) * 8) = hi;
    *(bf16x8*)(dst + (size_t)(c_lo * 16 + col) * 8) = lo;
}

// ---- Stage 1: LSH sign-hash — R5 VERBATIM (verified 57.0us, VGPR=60) -------
__global__ __launch_bounds__(512, 4) void hash_kernel(
    const __bf16* __restrict__ asw, const __bf16* __restrict__ rsw,
    unsigned int* __restrict__ codes_t)
{
    __shared__ __align__(16) unsigned char bsh[65536];

    const int t = threadIdx.x;
    const int lane = t & 63;
    const int quad = lane >> 4;       // 0..3
    const int col  = lane & 15;       // 0..15
    const int wv   = __builtin_amdgcn_readfirstlane(t >> 6);  // wave 0..7

    const int bid = blockIdx.x;       // 0..1087
    const int xcd = bid & 7;
    const int s   = bid >> 3;         // 0..135
    const int by  = s & 7;
    const int xq  = s >> 3;           // 0..16
    const int bx0 = xcd * XPX + xq * NTPB;

    const int wrow = (wv >> 1) * 32;  // 4 wave-rows of 32
    const int half = wv & 1;          // 2 wave-cols of 64 bits

    // A frag (ti, cbi) at pointer P: P + (ti*8 + cbi)*512 elems
    const __bf16* abase = asw + ((size_t)((bx0 * TM + wrow) >> 4)) * 4096
                              + (size_t)lane * 8;
#define ALOAD(P, ti, cbi) (*(const bf16x8*)((P) + ((ti) * 8 + (cbi)) * 512))
#define TILE_STRIDE 32768   /* 8 groups * 4096 elems */

    // B frag (tj, cbi) from LDS: half*32768 + tj*8192 + cbi*1024 + lane*16 B
    const unsigned char* bbase = bsh + half * 32768 + lane * 16;
#define BLOAD(tj, cbi) (*(const bf16x8*)(bbase + (tj) * 8192 + (cbi) * 1024))

    // Prefetch tile-0 iter-0 A frags; they complete by the staging barrier.
    bf16x8 xh0 = ALOAD(abase, 0, 0), xh1 = ALOAD(abase, 1, 0);
    bf16x8 xl0 = ALOAD(abase, 0, 2), xl1 = ALOAD(abase, 1, 2);
    bf16x8 yh0, yh1, yl0, yl1;

    // Stage this block's B tile (rsw + by*64KB, contiguous) into LDS, once.
    {
        const char* bsrc = (const char*)rsw + (size_t)by * 65536 + (size_t)t * 16;
        #pragma unroll
        for (int i = 0; i < 8; ++i)
            __builtin_amdgcn_global_load_lds(
                (const __attribute__((address_space(1))) unsigned int*)(bsrc + i * 8192),
                (__attribute__((address_space(3))) unsigned int*)(bsh + i * 8192 + t * 16),
                16, 0, 0);
    }
    __syncthreads();

#define MFMA __builtin_amdgcn_mfma_f32_16x16x32_bf16
#define BATCH(A0, A1, B0, B1, B2, B3)                       \
    acc[0][0] = MFMA(A0, B0, acc[0][0], 0, 0, 0);           \
    acc[0][1] = MFMA(A0, B1, acc[0][1], 0, 0, 0);           \
    acc[0][2] = MFMA(A0, B2, acc[0][2], 0, 0, 0);           \
    acc[0][3] = MFMA(A0, B3, acc[0][3], 0, 0, 0);           \
    acc[1][0] = MFMA(A1, B0, acc[1][0], 0, 0, 0);           \
    acc[1][1] = MFMA(A1, B1, acc[1][1], 0, 0, 0);           \
    acc[1][2] = MFMA(A1, B2, acc[1][2], 0, 0, 0);           \
    acc[1][3] = MFMA(A1, B3, acc[1][3], 0, 0, 0);

#define ITER(CH, cH0, cH1, cL0, cL1, PBASE, NH, nH0, nH1, nL0, nL1)     \
    {                                                                    \
        nH0 = ALOAD(PBASE, 0, NH);       nH1 = ALOAD(PBASE, 1, NH);      \
        nL0 = ALOAD(PBASE, 0, (NH) + 2); nL1 = ALOAD(PBASE, 1, (NH) + 2);\
        bf16x8 b0 = BLOAD(0, CH), b1 = BLOAD(1, CH),                     \
               b2 = BLOAD(2, CH), b3 = BLOAD(3, CH);                     \
        BATCH(cH0, cH1, b0, b1, b2, b3)      /* hi*hi */                 \
        BATCH(cL0, cL1, b0, b1, b2, b3)      /* lo*hi */                 \
        b0 = BLOAD(0, (CH) + 2); b1 = BLOAD(1, (CH) + 2);                \
        b2 = BLOAD(2, (CH) + 2); b3 = BLOAD(3, (CH) + 2);                \
        BATCH(cH0, cH1, b0, b1, b2, b3)      /* hi*lo */                 \
    }

    #pragma unroll
    for (int i = 0; i < NTPB; ++i) {
        const __bf16* ab = abase + (size_t)i * TILE_STRIDE;
        const __bf16* an = (i + 1 < NTPB) ? (ab + TILE_STRIDE) : ab;

        f32x4 acc[2][4];
        #pragma unroll
        for (int ti = 0; ti < 2; ++ti)
            #pragma unroll
            for (int tj = 0; tj < 4; ++tj)
                acc[ti][tj] = (f32x4){0.f, 0.f, 0.f, 0.f};

        // cbi_h sequence over (ks,kk) = (0,0),(0,1),(1,0),(1,1): {0,1,4,5}
        ITER(0, xh0, xh1, xl0, xl1, ab, 1, yh0, yh1, yl0, yl1)
        ITER(1, yh0, yh1, yl0, yl1, ab, 4, xh0, xh1, xl0, xl1)
        ITER(4, xh0, xh1, xl0, xl1, ab, 5, yh0, yh1, yl0, yl1)
        ITER(5, yh0, yh1, yl0, yl1, an, 0, xh0, xh1, xl0, xl1)

        // Sign-pack via ballot; C/D layout (m89): col=lane&15, row=quad*4+reg.
        // TRANSPOSED store: codes_t[word][row].
        const int row0 = (bx0 + i) * TM;
        #pragma unroll
        for (int ti = 0; ti < 2; ++ti) {
            #pragma unroll
            for (int rg = 0; rg < 4; ++rg) {
                unsigned long long b[4];
                #pragma unroll
                for (int tj = 0; tj < 4; ++tj)
                    b[tj] = __ballot(acc[ti][tj][rg] > 0.f);
                if (col < 2) {
                    const int w = col;
                    unsigned int lo16 = (unsigned int)(b[2 * w]     >> (16 * quad)) & 0xFFFFu;
                    unsigned int hi16 = (unsigned int)(b[2 * w + 1] >> (16 * quad)) & 0xFFFFu;
                    const int row = row0 + wrow + ti * 16 + quad * 4 + rg;
                    const int wg  = by * 4 + half * 2 + w;
                    codes_t[(size_t)wg * NROWS + row] = lo16 | (hi16 << 16);
                }
            }
        }
    }

#undef ITER
#undef BATCH
#undef MFMA
#undef BLOAD
#undef ALOAD
}

// ---- Stage 2: Hamming via i8 MFMA (R8: borrow-free +/-1 unpack) -----------
// R7's bug: (spread<<1) - 0x01010101 borrows ACROSS bytes (0-byte below a
// 1-byte corrupts it). Fix: r = ~((s<<8)-(s<<1)) = ~(s*254). Each byte of s
// is <=1, so s*254 has carry-free digits 254*bi; complement gives
// bi=1 -> 0x01 (+1), bi=0 -> 0xFF (-1). Exact, 3 ops.
// k-layout note: byte j of lane l carries the SAME hash-bit on the A and B
// side, so the dot is invariant to the HW (lane,byte)->k mapping.
// ham = (1024 - dot)/2 exactly; angle = pi/2048*(1024-dot).
#define SPREAD_PM1(nib, dst)                                             \
    {                                                                    \
        unsigned int s_ = (((nib) * 0x00204081u) & 0x01010101u);         \
        dst = ~((s_ << 8) - (s_ << 1));                                  \
    }

__global__ __launch_bounds__(256) void simmat_kernel(
    const unsigned int* __restrict__ codes_t,
    const int* __restrict__ qtok, const int* __restrict__ dtok,
    float* __restrict__ out)
{
    const int t = threadIdx.x;
    const int lane  = t & 63;
    const int col16 = lane & 15;
    const int ksub  = lane >> 4;          // 0..3 (k-slot within frag)
    const int wv    = t >> 6;             // 0..3

    const int bid   = blockIdx.x;         // 0..255
    const int batch = bid >> 2;           // (l*BAT + b), 0..63
    const int l     = batch >> 5;
    const int b     = batch & 31;
    const int n0    = ((bid & 3) * 4 + wv) * 64;   // wave's d-col base

    const int    qrow0 = batch * A_;                       // q rows
    const size_t drow0 = (size_t)NQROWS + (size_t)batch * B_ + n0;

    i32x4 acc[4][4];
    #pragma unroll
    for (int ti = 0; ti < 4; ++ti)
        #pragma unroll
        for (int tn = 0; tn < 4; ++tn)
            acc[ti][tn] = (i32x4){0, 0, 0, 0};

    const int sh = ksub * 8;   // byte within word for this lane's k-slot

    for (int kg = 0; kg < NW; ++kg) {     // 32 k-steps of K=32 bits
        const unsigned int* cw = codes_t + (size_t)kg * NROWS;
        long af[4], bf[4];
        #pragma unroll
        for (int ti = 0; ti < 4; ++ti) {
            unsigned int byte = (cw[qrow0 + ti * 16 + col16] >> sh) & 0xFFu;
            unsigned int lo, hi;
            SPREAD_PM1(byte & 0xFu, lo)
            SPREAD_PM1(byte >> 4,  hi)
            af[ti] = (long)(((unsigned long long)hi << 32) | lo);
        }
        #pragma unroll
        for (int tn = 0; tn < 4; ++tn) {
            unsigned int byte = (cw[drow0 + tn * 16 + col16] >> sh) & 0xFFu;
            unsigned int lo, hi;
            SPREAD_PM1(byte & 0xFu, lo)
            SPREAD_PM1(byte >> 4,  hi)
            bf[tn] = (long)(((unsigned long long)hi << 32) | lo);
        }
        #pragma unroll
        for (int ti = 0; ti < 4; ++ti)
            #pragma unroll
            for (int tn = 0; tn < 4; ++tn)
                acc[ti][tn] = __builtin_amdgcn_mfma_i32_16x16x32_i8(
                    af[ti], bf[tn], acc[ti][tn], 0, 0, 0);
    }

    // Epilogue: C/D layout col=lane&15 (d), row=ksub*4+rg (q).
    float dm[4];
    #pragma unroll
    for (int tn = 0; tn < 4; ++tn)
        dm[tn] = (dtok[b * B_ + n0 + tn * 16 + col16] != 0) ? 1.f : 0.f;

    float* obase = out + ((size_t)(b * L_ + l) * A_) * B_ + n0 + col16;
    #pragma unroll
    for (int ti = 0; ti < 4; ++ti) {
        #pragma unroll
        for (int rg = 0; rg < 4; ++rg) {
            const int a = ti * 16 + ksub * 4 + rg;
            const float qm = (qtok[b * A_ + a] != 0) ? 1.f : 0.f;
            #pragma unroll
            for (int tn = 0; tn < 4; ++tn) {
                // ham = (1024 - dot)/2 ; angle = pi/1024*ham = pi/2048*(1024-dot)
                float sim = __cosf((float)M_PI / 2048.0f *
                                   (float)(NBITS_ - acc[ti][tn][rg]));
                obase[(size_t)a * B_ + tn * 16] = sim * (qm * dm[tn]);
            }
        }
    }
}

extern "C" void kernel_launch(void* const* d_in, const int* in_sizes, int n_in,
                              void* d_out, int out_size, void* d_ws, size_t ws_size,
                              hipStream_t stream) {
    const float* qe  = (const float*)d_in[0];  // [L,BAT,A,D]
    const float* de  = (const float*)d_in[1];  // [L,BAT,B,D]
    const int* qtok  = (const int*)d_in[2];    // [BAT,A]
    const int* dtok  = (const int*)d_in[3];    // [BAT,B]
    const float* r   = (const float*)d_in[4];  // [NBITS,D]
    float* out = (float*)d_out;                // [BAT,L,A,B] fp32

    // ws: [0, 8.5MB) codes_t | [8.5, 9.0MB) rsw | [9.0MB, +34MB) asw
    unsigned int* codes_t = (unsigned int*)d_ws;                    // 8912896 B
    __bf16* rsw = (__bf16*)((char*)d_ws + 8912896);                 // 524288 B
    __bf16* asw = (__bf16*)((char*)d_ws + 8912896 + 524288);        // 35651584 B

    preswz_kernel<<<NAGRP + NBGRP, 256, 0, stream>>>(qe, de, r, asw, rsw);
    hash_kernel<<<(NXB / NTPB) * NYB, 512, 0, stream>>>(asw, rsw, codes_t);
    simmat_kernel<<<64 * 4, 256, 0, stream>>>(codes_t, qtok, dtok, out);
}

// Round 9
// 159.201 us; speedup vs baseline: 1.0781x; 1.0307x over previous
//
#include <hip/hip_runtime.h>
#include <math.h>

#define L_ 2
#define BAT_ 32
#define A_ 64
#define B_ 1024
#define D_ 128
#define NBITS_ 1024
#define NW 32                 // u32 words per code (1024 bits)
#define NQROWS (L_*BAT_*A_)   // 4096
#define NDROWS (L_*BAT_*B_)   // 65536
#define NROWS (NQROWS + NDROWS) // 69632
#define NAGRP (NROWS / 16)    // 4352 A-row groups of 16
#define NBGRP (NBITS_ / 16)   // 64 bit groups of 16

#define TM 128                // rows per tile
#define TN 128                // bits per tile
#define NXB (NROWS / TM)      // 544 x-tiles
#define NYB (NBITS_ / TN)     // 8 y-tiles
#define XPX (NXB / 8)         // 68 x-tiles per XCD
#define NTPB 4                // x-tiles per block (68 % 4 == 0)

typedef __bf16 bf16x8 __attribute__((ext_vector_type(8)));
typedef float  f32x4  __attribute__((ext_vector_type(4)));

// ---- Stage 0: split fp32 -> bf16 hi/lo AND swizzle into MFMA fragment order.
// UNCHANGED from R5 (verified).
__global__ __launch_bounds__(256) void preswz_kernel(
    const float* __restrict__ qe, const float* __restrict__ de,
    const float* __restrict__ r, __bf16* __restrict__ asw,
    __bf16* __restrict__ rsw)
{
    const int g = blockIdx.x;       // 0..4415: A groups then r groups
    const int t = threadIdx.x;
    const int ks = t >> 7, kk = (t >> 6) & 1, quad = (t >> 4) & 3, col = t & 15;

    const float* src;
    __bf16* dst;
    if (g < NAGRP) {
        int row = g * 16 + col;
        src = (row < NQROWS) ? (qe + (size_t)row * D_)
                             : (de + (size_t)(row - NQROWS) * D_);
        dst = asw + (size_t)g * 4096;
    } else {
        int bit = (g - NAGRP) * 16 + col;
        src = r + (size_t)bit * D_;
        dst = rsw + (size_t)(g - NAGRP) * 4096;
    }

    const int ko = ks * 64 + kk * 32 + quad * 8;
    float4 v0 = *(const float4*)(src + ko);
    float4 v1 = *(const float4*)(src + ko + 4);
    bf16x8 hi, lo;
    hi[0] = (__bf16)v0.x; hi[1] = (__bf16)v0.y;
    hi[2] = (__bf16)v0.z; hi[3] = (__bf16)v0.w;
    hi[4] = (__bf16)v1.x; hi[5] = (__bf16)v1.y;
    hi[6] = (__bf16)v1.z; hi[7] = (__bf16)v1.w;
    lo[0] = (__bf16)(v0.x - (float)hi[0]);
    lo[1] = (__bf16)(v0.y - (float)hi[1]);
    lo[2] = (__bf16)(v0.z - (float)hi[2]);
    lo[3] = (__bf16)(v0.w - (float)hi[3]);
    lo[4] = (__bf16)(v1.x - (float)hi[4]);
    lo[5] = (__bf16)(v1.y - (float)hi[5]);
    lo[6] = (__bf16)(v1.z - (float)hi[6]);
    lo[7] = (__bf16)(v1.w - (float)hi[7]);

    const int c_hi = ks * 16 + kk * 4 + quad;   // hl=0
    const int c_lo = c_hi + 8;                  // hl=1
    *(bf16x8*)(dst + (size_t)(c_hi * 16 + col) * 8) = hi;
    *(bf16x8*)(dst + (size_t)(c_lo * 16 + col) * 8) = lo;
}

// ---- Stage 1: LSH sign-hash — R5 + depth-1 B-hi prefetch -------------------
// R9: R5's verified structure (57us, VGPR 60+32acc=92) with ONE change:
// the B-hi fragment group is prefetched one ITER ahead (pb/qb rotation,
// same pattern as A's x/y), so each ITER's first 16 MFMAs start with ZERO
// lgkm wait; only the lo group's wait remains and it overlaps 2 BATCHes.
// Cost: +4 live frags = +16 VGPR -> ~108 total, still under the 128-reg
// quantum (the cliff that killed R4/R6). Everything else identical.
__global__ __launch_bounds__(512, 4) void hash_kernel(
    const __bf16* __restrict__ asw, const __bf16* __restrict__ rsw,
    unsigned int* __restrict__ codes_t)
{
    __shared__ __align__(16) unsigned char bsh[65536];

    const int t = threadIdx.x;
    const int lane = t & 63;
    const int quad = lane >> 4;       // 0..3
    const int col  = lane & 15;       // 0..15
    const int wv   = __builtin_amdgcn_readfirstlane(t >> 6);  // wave 0..7

    const int bid = blockIdx.x;       // 0..1087
    const int xcd = bid & 7;
    const int s   = bid >> 3;         // 0..135
    const int by  = s & 7;
    const int xq  = s >> 3;           // 0..16
    const int bx0 = xcd * XPX + xq * NTPB;

    const int wrow = (wv >> 1) * 32;  // 4 wave-rows of 32
    const int half = wv & 1;          // 2 wave-cols of 64 bits

    // A frag (ti, cbi) at pointer P: P + (ti*8 + cbi)*512 elems
    const __bf16* abase = asw + ((size_t)((bx0 * TM + wrow) >> 4)) * 4096
                              + (size_t)lane * 8;
#define ALOAD(P, ti, cbi) (*(const bf16x8*)((P) + ((ti) * 8 + (cbi)) * 512))
#define TILE_STRIDE 32768   /* 8 groups * 4096 elems */

    // B frag (tj, cbi) from LDS: half*32768 + tj*8192 + cbi*1024 + lane*16 B
    const unsigned char* bbase = bsh + half * 32768 + lane * 16;
#define BLOAD(tj, cbi) (*(const bf16x8*)(bbase + (tj) * 8192 + (cbi) * 1024))

    // Prefetch tile-0 iter-0 A frags; they complete by the staging barrier.
    bf16x8 xh0 = ALOAD(abase, 0, 0), xh1 = ALOAD(abase, 1, 0);
    bf16x8 xl0 = ALOAD(abase, 0, 2), xl1 = ALOAD(abase, 1, 2);
    bf16x8 yh0, yh1, yl0, yl1;

    // Stage this block's B tile (rsw + by*64KB, contiguous) into LDS, once.
    {
        const char* bsrc = (const char*)rsw + (size_t)by * 65536 + (size_t)t * 16;
        #pragma unroll
        for (int i = 0; i < 8; ++i)
            __builtin_amdgcn_global_load_lds(
                (const __attribute__((address_space(1))) unsigned int*)(bsrc + i * 8192),
                (__attribute__((address_space(3))) unsigned int*)(bsh + i * 8192 + t * 16),
                16, 0, 0);
    }
    __syncthreads();

    // B-hi prefetch rotation: load CH=0 hi group for tile 0.
    bf16x8 pb0 = BLOAD(0, 0), pb1 = BLOAD(1, 0),
           pb2 = BLOAD(2, 0), pb3 = BLOAD(3, 0);
    bf16x8 qb0, qb1, qb2, qb3;

#define MFMA __builtin_amdgcn_mfma_f32_16x16x32_bf16
#define BATCH(A0, A1, B0, B1, B2, B3)                       \
    acc[0][0] = MFMA(A0, B0, acc[0][0], 0, 0, 0);           \
    acc[0][1] = MFMA(A0, B1, acc[0][1], 0, 0, 0);           \
    acc[0][2] = MFMA(A0, B2, acc[0][2], 0, 0, 0);           \
    acc[0][3] = MFMA(A0, B3, acc[0][3], 0, 0, 0);           \
    acc[1][0] = MFMA(A1, B0, acc[1][0], 0, 0, 0);           \
    acc[1][1] = MFMA(A1, B1, acc[1][1], 0, 0, 0);           \
    acc[1][2] = MFMA(A1, B2, acc[1][2], 0, 0, 0);           \
    acc[1][3] = MFMA(A1, B3, acc[1][3], 0, 0, 0);

// One (ks,kk) step. CH = current hi chunk group (already in PB0..3).
//  1. prefetch next A frag group (global)
//  2. prefetch NEXT iter's hi B group into NB0..3 (ds_read, drains under MFMAs)
//  3. read current lo B group c0..3 (wait overlaps first 2 BATCHes)
//  4. hh + lh on PB (no wait), hl on c.
#define ITER(CH, PB0, PB1, PB2, PB3, NCH, NB0, NB1, NB2, NB3,            \
             cH0, cH1, cL0, cL1, PBASE, NH, nH0, nH1, nL0, nL1)          \
    {                                                                    \
        nH0 = ALOAD(PBASE, 0, NH);       nH1 = ALOAD(PBASE, 1, NH);      \
        nL0 = ALOAD(PBASE, 0, (NH) + 2); nL1 = ALOAD(PBASE, 1, (NH) + 2);\
        NB0 = BLOAD(0, NCH); NB1 = BLOAD(1, NCH);                        \
        NB2 = BLOAD(2, NCH); NB3 = BLOAD(3, NCH);                        \
        bf16x8 c0 = BLOAD(0, (CH) + 2), c1 = BLOAD(1, (CH) + 2),         \
               c2 = BLOAD(2, (CH) + 2), c3 = BLOAD(3, (CH) + 2);         \
        BATCH(cH0, cH1, PB0, PB1, PB2, PB3)   /* hi*hi */                \
        BATCH(cL0, cL1, PB0, PB1, PB2, PB3)   /* lo*hi */                \
        BATCH(cH0, cH1, c0, c1, c2, c3)       /* hi*lo */                \
    }

    #pragma unroll
    for (int i = 0; i < NTPB; ++i) {
        const __bf16* ab = abase + (size_t)i * TILE_STRIDE;
        const __bf16* an = (i + 1 < NTPB) ? (ab + TILE_STRIDE) : ab;

        f32x4 acc[2][4];
        #pragma unroll
        for (int ti = 0; ti < 2; ++ti)
            #pragma unroll
            for (int tj = 0; tj < 4; ++tj)
                acc[ti][tj] = (f32x4){0.f, 0.f, 0.f, 0.f};

        // cbi_h sequence over (ks,kk): {0,1,4,5}; last ITER prefetches CH=0
        // (same B data for the next tile -> rotation stays uniform).
        ITER(0, pb0, pb1, pb2, pb3, 1, qb0, qb1, qb2, qb3,
             xh0, xh1, xl0, xl1, ab, 1, yh0, yh1, yl0, yl1)
        ITER(1, qb0, qb1, qb2, qb3, 4, pb0, pb1, pb2, pb3,
             yh0, yh1, yl0, yl1, ab, 4, xh0, xh1, xl0, xl1)
        ITER(4, pb0, pb1, pb2, pb3, 5, qb0, qb1, qb2, qb3,
             xh0, xh1, xl0, xl1, ab, 5, yh0, yh1, yl0, yl1)
        ITER(5, qb0, qb1, qb2, qb3, 0, pb0, pb1, pb2, pb3,
             yh0, yh1, yl0, yl1, an, 0, xh0, xh1, xl0, xl1)

        // Sign-pack via ballot; C/D layout (m89): col=lane&15, row=quad*4+reg.
        // TRANSPOSED store: codes_t[word][row].
        const int row0 = (bx0 + i) * TM;
        #pragma unroll
        for (int ti = 0; ti < 2; ++ti) {
            #pragma unroll
            for (int rg = 0; rg < 4; ++rg) {
                unsigned long long b[4];
                #pragma unroll
                for (int tj = 0; tj < 4; ++tj)
                    b[tj] = __ballot(acc[ti][tj][rg] > 0.f);
                if (col < 2) {
                    const int w = col;
                    unsigned int lo16 = (unsigned int)(b[2 * w]     >> (16 * quad)) & 0xFFFFu;
                    unsigned int hi16 = (unsigned int)(b[2 * w + 1] >> (16 * quad)) & 0xFFFFu;
                    const int row = row0 + wrow + ti * 16 + quad * 4 + rg;
                    const int wg  = by * 4 + half * 2 + w;
                    codes_t[(size_t)wg * NROWS + row] = lo16 | (hi16 << 16);
                }
            }
        }
    }

#undef ITER
#undef BATCH
#undef MFMA
#undef BLOAD
#undef ALOAD
}

// ---- Stage 2: Hamming -> cos (HW v_cos) -> mask -> out ---------------------
// REVERTED to the verified popc version (R5). R8's i8-MFMA rewrite was +6us:
// proper wave-normalized arithmetic puts this kernel at ~5us (6.3M wave-ops
// x 2cyc / 1024 SIMDs), already near its VALU floor; the MFMA version had
// only 1 wave/SIMD and a long dependent unpack chain. Lesson: rule 14.
__global__ __launch_bounds__(256) void simmat_kernel(
    const unsigned int* __restrict__ codes_t,
    const int* __restrict__ qtok, const int* __restrict__ dtok,
    float* __restrict__ out)
{
    __shared__ unsigned int qc[8 * 36];

    const int blk  = blockIdx.x;
    const int ct   = blk & 3;
    const int asub = (blk >> 2) & 7;
    const int b    = (blk >> 5) & 31;
    const int l    = blk >> 10;
    const int t    = threadIdx.x;

    const int a0 = asub * 8;
    const int qrow0 = (l * BAT_ + b) * A_ + a0;
    if (t < 256) {
        int w = t >> 3, a = t & 7;
        qc[a * 36 + w] = codes_t[(size_t)w * NROWS + qrow0 + a];
    }
    __syncthreads();

    const int c = ct * 256 + t;
    const size_t drow = (size_t)NQROWS + (size_t)(l * BAT_ + b) * B_ + c;
    unsigned int dc[NW];
    #pragma unroll
    for (int w = 0; w < NW; ++w) dc[w] = codes_t[(size_t)w * NROWS + drow];
    const float dm = (dtok[b * B_ + c] != 0) ? 1.f : 0.f;

    float* obase = out + ((size_t)((b * L_ + l) * A_ + a0)) * B_ + c;
    #pragma unroll
    for (int ai = 0; ai < 8; ++ai) {
        int ham = 0;
        #pragma unroll
        for (int m = 0; m < 8; ++m) {
            uint4 qv = *(const uint4*)(&qc[ai * 36 + m * 4]);
            ham += __popc(qv.x ^ dc[4 * m])     + __popc(qv.y ^ dc[4 * m + 1])
                 + __popc(qv.z ^ dc[4 * m + 2]) + __popc(qv.w ^ dc[4 * m + 3]);
        }
        const float qmv = (qtok[b * A_ + a0 + ai] != 0) ? 1.f : 0.f;
        float sim = __cosf((float)M_PI / (float)NBITS_ * (float)ham);
        obase[(size_t)ai * B_] = sim * (qmv * dm);
    }
}

extern "C" void kernel_launch(void* const* d_in, const int* in_sizes, int n_in,
                              void* d_out, int out_size, void* d_ws, size_t ws_size,
                              hipStream_t stream) {
    const float* qe  = (const float*)d_in[0];  // [L,BAT,A,D]
    const float* de  = (const float*)d_in[1];  // [L,BAT,B,D]
    const int* qtok  = (const int*)d_in[2];    // [BAT,A]
    const int* dtok  = (const int*)d_in[3];    // [BAT,B]
    const float* r   = (const float*)d_in[4];  // [NBITS,D]
    float* out = (float*)d_out;                // [BAT,L,A,B] fp32

    // ws: [0, 8.5MB) codes_t | [8.5, 9.0MB) rsw | [9.0MB, +34MB) asw
    unsigned int* codes_t = (unsigned int*)d_ws;                    // 8912896 B
    __bf16* rsw = (__bf16*)((char*)d_ws + 8912896);                 // 524288 B
    __bf16* asw = (__bf16*)((char*)d_ws + 8912896 + 524288);        // 35651584 B

    preswz_kernel<<<NAGRP + NBGRP, 256, 0, stream>>>(qe, de, r, asw, rsw);
    hash_kernel<<<(NXB / NTPB) * NYB, 512, 0, stream>>>(asw, rsw, codes_t);
    simmat_kernel<<<L_ * BAT_ * 8 * 4, 256, 0, stream>>>(codes_t, qtok, dtok, out);
}